// Round 1
// baseline (63.180 us; speedup 1.0000x reference)
//
#include <hip/hip_runtime.h>
#include <hip/hip_bf16.h>

#define VOCAB 50000
#define HID   256
#define BATCH 512
#define GH    768   // 3*H

typedef __attribute__((ext_vector_type(8))) __bf16 bf16x8;
typedef __attribute__((ext_vector_type(4))) float f32x4;

union BFrag {
    bf16x8 v;
    uint4  q;
    unsigned short u[8];
};

__device__ __forceinline__ unsigned short f2bf(float f) {
    unsigned int x = __builtin_bit_cast(unsigned int, f);
    x += 0x7FFFu + ((x >> 16) & 1u);          // round-to-nearest-even
    return (unsigned short)(x >> 16);
}

__device__ __forceinline__ float fast_sigmoid(float x) {
    return 1.0f / (1.0f + __expf(-x));
}
__device__ __forceinline__ float fast_tanh(float x) {
    return 1.0f - 2.0f / (1.0f + __expf(2.0f * x));
}

// C[M x Ncols] = A[M x 256] @ Bm[Ncols x 256]^T  (both K-major, K=256, no K-loop)
// EPI  0: raw f32 store   1: tanh(acc + bias[col])
// ASRC 0: A is f32        1: A is bf16 (ushort)
// Block: 256 threads (4 waves). BN=64 cols/block (wave w owns cols w*16..w*16+15).
// M processed in chunks of 64 rows; B-fragments live in registers across chunks.
template <int EPI, int ASRC>
__global__ __launch_bounds__(256) void gemm_nt(
    const void* __restrict__ Asrc, const float* __restrict__ Bm,
    float* __restrict__ C, const float* __restrict__ bias,
    int Ncols, int mChunks)
{
    __shared__ char ldsA[64 * 512];           // 64 rows x 256 bf16, XOR-swizzled

    const int tid  = threadIdx.x;
    const int wid  = tid >> 6;
    const int lane = tid & 63;
    const int r    = lane & 15;               // fragment row/col index
    const int g    = lane >> 4;               // k-group
    const int nbase = blockIdx.x * 64;
    const int col   = nbase + wid * 16 + r;   // output column == B row
    const int bcol  = col < Ncols ? col : (Ncols - 1);

    // ---- load B fragments once, convert f32 -> bf16, keep in registers ----
    BFrag bf[8];
    {
        const float4* wrow = reinterpret_cast<const float4*>(Bm + (size_t)bcol * 256);
        #pragma unroll
        for (int kk = 0; kk < 8; kk++) {
            float4 lo = wrow[kk * 8 + g * 2];
            float4 hi = wrow[kk * 8 + g * 2 + 1];
            bf[kk].u[0] = f2bf(lo.x); bf[kk].u[1] = f2bf(lo.y);
            bf[kk].u[2] = f2bf(lo.z); bf[kk].u[3] = f2bf(lo.w);
            bf[kk].u[4] = f2bf(hi.x); bf[kk].u[5] = f2bf(hi.y);
            bf[kk].u[6] = f2bf(hi.z); bf[kk].u[7] = f2bf(hi.w);
        }
    }
    float biasv = 0.0f;
    if (EPI == 1) biasv = bias[bcol];

    for (int c = 0; c < mChunks; c++) {
        const int mbase = (blockIdx.y * mChunks + c) * 64;

        // ---- stage A chunk (64 x 256) into swizzled LDS ----
        if (ASRC == 1) {
            const uint4* src = reinterpret_cast<const uint4*>(
                (const unsigned short*)Asrc + (size_t)mbase * 256);
            #pragma unroll
            for (int i = 0; i < 8; i++) {
                int u   = tid + i * 256;            // 0..2047 16B units
                int row = u >> 5, c16 = u & 31;
                uint4 vv = src[row * 32 + c16];
                int byte = (row * 512 + c16 * 16) ^ ((row & 7) << 4);
                *reinterpret_cast<uint4*>(&ldsA[byte]) = vv;
            }
        } else {
            const float4* src = reinterpret_cast<const float4*>(
                (const float*)Asrc + (size_t)mbase * 256);
            #pragma unroll
            for (int i = 0; i < 8; i++) {
                int u   = tid + i * 256;
                int row = u >> 5, c16 = u & 31;
                float4 lo = src[row * 64 + c16 * 2];
                float4 hi = src[row * 64 + c16 * 2 + 1];
                BFrag t;
                t.u[0] = f2bf(lo.x); t.u[1] = f2bf(lo.y);
                t.u[2] = f2bf(lo.z); t.u[3] = f2bf(lo.w);
                t.u[4] = f2bf(hi.x); t.u[5] = f2bf(hi.y);
                t.u[6] = f2bf(hi.z); t.u[7] = f2bf(hi.w);
                int byte = (row * 512 + c16 * 16) ^ ((row & 7) << 4);
                *reinterpret_cast<uint4*>(&ldsA[byte]) = t.q;
            }
        }
        __syncthreads();

        // ---- MFMA: 4 row-fragments x 8 k-steps ----
        f32x4 acc[4];
        #pragma unroll
        for (int m = 0; m < 4; m++) acc[m] = (f32x4){0.f, 0.f, 0.f, 0.f};

        #pragma unroll
        for (int kk = 0; kk < 8; kk++) {
            #pragma unroll
            for (int m = 0; m < 4; m++) {
                int arow = m * 16 + r;
                int byte = (arow * 512 + kk * 64 + g * 16) ^ ((arow & 7) << 4);
                BFrag a;
                a.q = *reinterpret_cast<const uint4*>(&ldsA[byte]);
                acc[m] = __builtin_amdgcn_mfma_f32_16x16x32_bf16(a.v, bf[kk].v, acc[m], 0, 0, 0);
            }
        }

        // ---- epilogue ----
        if (col < Ncols) {
            #pragma unroll
            for (int m = 0; m < 4; m++) {
                #pragma unroll
                for (int j = 0; j < 4; j++) {
                    int row = mbase + m * 16 + g * 4 + j;
                    float v = acc[m][j];
                    if (EPI == 1) v = fast_tanh(v + biasv);
                    C[(size_t)row * Ncols + col] = v;
                }
            }
        }
        __syncthreads();   // before next chunk overwrites LDS
    }
}

// GRU gates: x-gather from w_ih + gate math. One block per batch row, thread = k.
__global__ __launch_bounds__(256) void gru_gate(
    const int* __restrict__ inp, const float* __restrict__ hidden,
    const float* __restrict__ w_ih, const float* __restrict__ b_ih,
    const float* __restrict__ b_hh, const float* __restrict__ hproj,
    float* __restrict__ h1out, unsigned short* __restrict__ h1bf)
{
    const int b = blockIdx.x;
    const int k = threadIdx.x;
    const int c = inp[b];

    float xr = w_ih[(size_t)k * VOCAB + c]         + b_ih[k];
    float xz = w_ih[(size_t)(k + 256) * VOCAB + c] + b_ih[k + 256];
    float xn = w_ih[(size_t)(k + 512) * VOCAB + c] + b_ih[k + 512];

    float hr = hproj[b * GH + k]       + b_hh[k];
    float hz = hproj[b * GH + 256 + k] + b_hh[k + 256];
    float hn = hproj[b * GH + 512 + k] + b_hh[k + 512];

    float rg = fast_sigmoid(xr + hr);
    float zg = fast_sigmoid(xz + hz);
    float ng = fast_tanh(xn + rg * hn);
    float h0 = hidden[b * HID + k];
    float h1 = (1.0f - zg) * ng + zg * h0;

    h1out[b * HID + k] = h1;
    h1bf[b * HID + k]  = f2bf(h1);
}

extern "C" void kernel_launch(void* const* d_in, const int* in_sizes, int n_in,
                              void* d_out, int out_size, void* d_ws, size_t ws_size,
                              hipStream_t stream) {
    const int*   input  = (const int*)  d_in[0];
    // d_in[1] = target (unused)
    const float* hidden = (const float*)d_in[2];
    const float* w_ih   = (const float*)d_in[3];
    const float* w_hh   = (const float*)d_in[4];
    const float* b_ih   = (const float*)d_in[5];
    const float* b_hh   = (const float*)d_in[6];
    const float* w_out  = (const float*)d_in[7];
    const float* b_out  = (const float*)d_in[8];

    float* logit = (float*)d_out;                            // [512, 50000]
    float* h1    = (float*)d_out + (size_t)BATCH * VOCAB;    // [512, 256]

    float*          hproj = (float*)d_ws;                                   // 512*768 f32
    unsigned short* h1bf  = (unsigned short*)((char*)d_ws + (size_t)BATCH * GH * 4);

    // K1: hproj = h0 @ w_hh^T   (512 x 768, K=256)
    dim3 g1(GH / 64, BATCH / 64);           // (12, 8), mChunks = 1
    gemm_nt<0, 0><<<g1, 256, 0, stream>>>(hidden, w_hh, hproj, nullptr, GH, 1);

    // K2: gates -> h1 (f32 into d_out tail, bf16 into ws)
    gru_gate<<<BATCH, 256, 0, stream>>>(input, hidden, w_ih, b_ih, b_hh, hproj, h1, h1bf);

    // K3: logit = tanh(h1 @ w_out^T + b_out)   (512 x 50000, K=256)
    dim3 g3((VOCAB + 63) / 64, 1);          // 782 blocks, 8 m-chunks each
    gemm_nt<1, 1><<<g3, 256, 0, stream>>>(h1bf, w_out, logit, b_out, VOCAB, 8);
}